// Round 6
// baseline (378.017 us; speedup 1.0000x reference)
//
#include <hip/hip_runtime.h>
#include <hip/hip_bf16.h>
#include <cstdint>
#include <cstddef>

namespace {

constexpr int kB = 512, kT = 32, kH = 768, kF = 3072, kE = 3;
constexpr int kMaxTiles = 131;   // sum ceil(cnt_e/4) <= 131
constexpr int kMaxChunk = 131;
constexpr int kHbufTile  = 128 * kF;   // 393216 elts per tile
constexpr int kXconvB = kT * kH;       // 24576 elts per batch

typedef __attribute__((ext_vector_type(8))) short short8;
typedef __attribute__((ext_vector_type(4))) float f32x4;

__device__ __forceinline__ void gld_lds16(const void* g, void* l) {
  __builtin_amdgcn_global_load_lds(
      (const __attribute__((address_space(1))) void*)g,
      (__attribute__((address_space(3))) void*)l, 16, 0, 0);
}

__device__ __forceinline__ float bf2f(__hip_bfloat16 v) { return __bfloat162float(v); }
__device__ __forceinline__ float bfu(unsigned short u) {
  return __uint_as_float(((unsigned)u) << 16);
}
__device__ __forceinline__ unsigned short f2bfb(float f) {
  __hip_bfloat16 h = __float2bfloat16(f);
  return *reinterpret_cast<unsigned short*>(&h);
}

// exact-grade gelu: Abramowitz-Stegun 7.1.26 erf, |err| <= 1.5e-7
__device__ __forceinline__ float gelu_f(float v) {
  float av = fabsf(v);
  float z = av * 0.70710678118654752f;
  float t = __builtin_amdgcn_rcpf(fmaf(0.3275911f, z, 1.0f));
  float p = fmaf(fmaf(fmaf(fmaf(1.061405429f, t, -1.453152027f), t, 1.421413741f),
                      t, -0.284496736f), t, 0.254829592f) * t;
  float er = fmaf(-p, __expf(-z * z), 1.0f);   // erf(z), z >= 0
  return 0.5f * v + 0.5f * av * er;
}

// ---------------- fused: sniff + route + convert + (last block) tile packing ----------------
// one block per batch; reads x exactly once.
// xconv[b][t32(24)][mm(32)][qp(4)][8] ; content col = t32*32 + (qp^((mm>>1)&3))*8
__global__ __launch_bounds__(256)
void k_prep_x(const void* __restrict__ xv, const void* __restrict__ Wgv,
              float* __restrict__ wsel,
              int* __restrict__ cntTk,            // cnt[3] + ticket
              int* __restrict__ lists,
              int* __restrict__ tileExpert, int* __restrict__ tileBatch,
              int* __restrict__ numTiles,
              __hip_bfloat16* __restrict__ xconv) {
  __shared__ __align__(16) unsigned short xs[32][772];
  __shared__ float red[3][256];
  __shared__ int sniffX, sniffG, lastFlag;
  __shared__ int csh[3];
  int b = blockIdx.x, tid = threadIdx.x;
  if (tid == 0) { sniffX = 0; sniffG = 0; }
  __syncthreads();
  // head sniff (first blocks of each buffer; all blocks agree deterministically)
  {
    const unsigned short* xw = (const unsigned short*)xv;
    const unsigned short* gw = (const unsigned short*)Wgv;
    int lx = 0, lg = 0;
#pragma unroll
    for (int i = 0; i < 16; ++i) lx += (((xw[tid + 256 * i] >> 7) & 0xFF) >= 0xC0);
#pragma unroll
    for (int i = 0; i < 8; ++i) lg += (((gw[tid + 256 * i] >> 7) & 0xFF) >= 0xC0);
    atomicAdd(&sniffX, lx);
    atomicAdd(&sniffG, lg);
  }
  __syncthreads();
  bool fx = (sniffX > 64), fg = (sniffG > 32);

  // load batch into LDS (bf16 words) + accumulate column means in f32 (r5 route math)
  float a0 = 0.f, a1 = 0.f, a2 = 0.f;
  if (tid < 192) {   // 192 * 4 cols = 768
    float m0 = 0.f, m1 = 0.f, m2 = 0.f, m3 = 0.f;
    if (fx) {
      const float4* xr = (const float4*)((const float*)xv + (size_t)b * kT * kH) + tid;
#pragma unroll 8
      for (int t = 0; t < kT; ++t) {
        float4 u = xr[t * 192];
        m0 += u.x; m1 += u.y; m2 += u.z; m3 += u.w;
        ushort4 v;
        v.x = f2bfb(u.x); v.y = f2bfb(u.y); v.z = f2bfb(u.z); v.w = f2bfb(u.w);
        *(ushort4*)&xs[t][tid * 4] = v;
      }
    } else {
      const ushort4* xr = (const ushort4*)((const unsigned short*)xv + (size_t)b * kT * kH) + tid;
#pragma unroll 8
      for (int t = 0; t < kT; ++t) {
        ushort4 u = xr[t * 192];
        m0 += bfu(u.x); m1 += bfu(u.y); m2 += bfu(u.z); m3 += bfu(u.w);
        *(ushort4*)&xs[t][tid * 4] = u;
      }
    }
    const float inv = 1.f / kT;
    m0 *= inv; m1 *= inv; m2 *= inv; m3 *= inv;
#pragma unroll
    for (int e = 0; e < kE; ++e) {
      float w0, w1v, w2v, w3;
      int base = e * kH + tid * 4;
      if (fg) {
        float4 u = *(const float4*)((const float*)Wgv + base);
        w0 = u.x; w1v = u.y; w2v = u.z; w3 = u.w;
      } else {
        ushort4 u = *(const ushort4*)((const unsigned short*)Wgv + base);
        w0 = bfu(u.x); w1v = bfu(u.y); w2v = bfu(u.z); w3 = bfu(u.w);
      }
      float d = m0 * w0 + m1 * w1v + m2 * w2v + m3 * w3;
      if (e == 0) a0 = d; else if (e == 1) a1 = d; else a2 = d;
    }
  }
  red[0][tid] = a0; red[1][tid] = a1; red[2][tid] = a2;
  __syncthreads();
  for (int s2 = 128; s2 > 0; s2 >>= 1) {
    if (tid < s2) {
      red[0][tid] += red[0][tid + s2];
      red[1][tid] += red[1][tid + s2];
      red[2][tid] += red[2][tid + s2];
    }
    __syncthreads();
  }
  if (tid == 0) {
    float l0 = red[0][0], l1 = red[1][0], l2 = red[2][0];
    int am = 0; float mx = l0;
    if (l1 > mx) { mx = l1; am = 1; }
    if (l2 > mx) { mx = l2; am = 2; }
    float e0 = expf(l0 - mx), e1 = expf(l1 - mx), e2 = expf(l2 - mx);
    float inv = 1.f / (e0 + e1 + e2);
    float sc = (am == 0 ? e0 : (am == 1 ? e1 : e2)) * inv;
    wsel[b] = sc;
    int pos = atomicAdd(&cntTk[am], 1);
    lists[am * kB + pos] = b;
    __threadfence();                       // publish lists/cnt (release)
    int tk = atomicAdd(&cntTk[3], 1);
    lastFlag = (tk == kB - 1) ? 1 : 0;
  }

  // repack xs -> xconv[b] (ffn1 A-staging order), contiguous 16B stores
  __syncthreads();
  unsigned short* dst = (unsigned short*)xconv + (size_t)b * kXconvB;
#pragma unroll
  for (int i = 0; i < 12; ++i) {
    int g = i * 256 + tid;               // 0..3071
    int t32 = g >> 7, r = g & 127, mm = r >> 2, qp = r & 3;
    int col = t32 * 32 + (qp ^ ((mm >> 1) & 3)) * 8;
    ushort4 lo = *(const ushort4*)&xs[mm][col];
    ushort4 hi = *(const ushort4*)&xs[mm][col + 4];
    short8 v;
    v[0] = lo.x; v[1] = lo.y; v[2] = lo.z; v[3] = lo.w;
    v[4] = hi.x; v[5] = hi.y; v[6] = hi.z; v[7] = hi.w;
    *(short8*)(dst + g * 8) = v;
  }

  // last block: parallel tile packing
  if (lastFlag) {
    __threadfence();                       // acquire
    if (tid < 3) csh[tid] = cntTk[tid];
    __syncthreads();
    int c0 = csh[0], c1 = csh[1], c2 = csh[2];
    int t0 = ((c0 + 3) & ~3) >> 2;
    int t1 = ((c1 + 3) & ~3) >> 2;
    int t2 = ((c2 + 3) & ~3) >> 2;
    int total = t0 + t1 + t2;
    if (tid == 0) *numTiles = total;
    for (int t = tid; t < kMaxTiles; t += 256) {
      int e = 0, base = 0, cc = 0;
      bool pad = false;
      if (t < t0) { e = 0; base = t; cc = c0; }
      else if (t < t0 + t1) { e = 1; base = t - t0; cc = c1; }
      else if (t < total) { e = 2; base = t - t0 - t1; cc = c2; }
      else pad = true;
      if (pad) {
        tileExpert[t] = 0;
        for (int s = 0; s < 4; ++s) tileBatch[t * 4 + s] = -1;
      } else {
        tileExpert[t] = e;
        for (int s = 0; s < 4; ++s) {
          int i = base * 4 + s;
          tileBatch[t * 4 + s] = (i < cc) ? lists[e * kB + i] : -1;
        }
      }
    }
  }
}

// ---------------- fused transpose + convert: both weight tensors, local head-sniff ----------------
// z<3: W1 [e][H][F] -> w1t [e][F][H]; z>=3: W2 [e][F][H] -> w2t [e][H][F]
__global__ __launch_bounds__(256)
void k_transpose6(const void* __restrict__ w1src, const void* __restrict__ w2src,
                  __hip_bfloat16* __restrict__ w1dst, __hip_bfloat16* __restrict__ w2dst) {
  int z = blockIdx.z;
  bool isW1 = (z < 3);
  int e = isW1 ? z : z - 3;
  __shared__ __align__(16) unsigned short t[64][73];
  __shared__ int cnt_s;
  if (threadIdx.x == 0) cnt_s = 0;
  __syncthreads();
  {
    const unsigned short* hw = (const unsigned short*)(isW1 ? w1src : w2src);
    int local = 0;
#pragma unroll
    for (int i = 0; i < 16; ++i)
      local += (((hw[threadIdx.x + 256 * i] >> 7) & 0xFF) >= 0xC0);
    atomicAdd(&cnt_s, local);
  }
  __syncthreads();
  bool f32 = (cnt_s > 64);
  const float* sf = (const float*)(isW1 ? w1src : w2src);
  const unsigned short* sb = (const unsigned short*)(isW1 ? w1src : w2src);
  unsigned short* dst = (unsigned short*)(isW1 ? w1dst : w2dst);
  int K = isW1 ? kH : kF, N = isW1 ? kF : kH;
  int ntx = N / 64;
  int bx = blockIdx.x;
  int n0 = (bx % ntx) * 64, k0 = (bx / ntx) * 64;
  size_t eoff = (size_t)e * K * N;
  int tr = threadIdx.x >> 4;
  int tc4 = (threadIdx.x & 15) * 4;
#pragma unroll
  for (int i = 0; i < 4; ++i) {
    int r = tr + 16 * i;
    size_t idx = eoff + (size_t)(k0 + r) * N + n0 + tc4;
    if (f32) {
      float4 u = *(const float4*)(sf + idx);
      t[r][tc4] = f2bfb(u.x); t[r][tc4 + 1] = f2bfb(u.y);
      t[r][tc4 + 2] = f2bfb(u.z); t[r][tc4 + 3] = f2bfb(u.w);
    } else {
      ushort4 u = *(const ushort4*)(sb + idx);
      t[r][tc4] = u.x; t[r][tc4 + 1] = u.y; t[r][tc4 + 2] = u.z; t[r][tc4 + 3] = u.w;
    }
  }
  __syncthreads();
#pragma unroll
  for (int i = 0; i < 4; ++i) {
    int rn = tr + 16 * i;
    ushort4 v;
    v.x = t[tc4][rn]; v.y = t[tc4 + 1][rn]; v.z = t[tc4 + 2][rn]; v.w = t[tc4 + 3][rn];
    *(ushort4*)(dst + eoff + (size_t)(n0 + rn) * K + k0 + tc4) = v;
  }
}

// ---------------- GEMM1: h = gelu(x @ W1[e] + b1), hbuf in ffn2-A-staging order ----------------
// A staged straight from per-batch xconv via per-thread batch-indirect pointers.
__global__ __launch_bounds__(256, 2)
void k_ffn1(const __hip_bfloat16* __restrict__ xconv,
            const __hip_bfloat16* __restrict__ w1t,  // [E][F][H] bf16
            const __hip_bfloat16* __restrict__ b1,
            const int* __restrict__ tileExpert,
            const int* __restrict__ tileBatch,
            const int* __restrict__ numTiles,
            int tileOff,
            __hip_bfloat16* __restrict__ hbuf) {
  int j = blockIdx.y;
  int local = j / 3;
  int tile = local + tileOff;
  if (tile >= *numTiles) return;
  int nIdx = 8 * (j % 3) + blockIdx.x;
  int nbase = nIdx * 128;
  int e = tileExpert[tile];
  __shared__ __align__(16) short ldsbuf[16384];   // A: [0,8192) B: [8192,16384)
  short* ldsA = ldsbuf;
  short* ldsB = ldsbuf + 8192;
  int tid = threadIdx.x;
  int lane = tid & 63, wid = tid >> 6;
  int wm = wid >> 1, wn = wid & 1;
  int lane16 = lane & 15, qf = lane >> 4;
  int swzl = (lane16 >> 1) & 3;
  int qx = (qf ^ swzl) * 8;

  // A staging addresses: slots it*256+tid; m = (tid>>2) + (it&1)*64, kk = it>>1
  int slotLo = tid >> 7;                             // (tid>>2)>>5
  int b0v = tileBatch[tile * 4];                     // slot 0 always valid
  int bLo = tileBatch[tile * 4 + slotLo];
  int bHi = tileBatch[tile * 4 + 2 + slotLo];
  if (bLo < 0) bLo = b0v;
  if (bHi < 0) bHi = b0v;
  int mmLo = (tid >> 2) & 31;
  int q = (tid & 3) ^ ((tid >> 3) & 3);
  int qp = q ^ ((mmLo >> 1) & 3);
  int baseOff = (mmLo * 4 + qp) * 8;                 // within 1024-elt t32 group
  const __hip_bfloat16* pLo = xconv + (size_t)bLo * kXconvB + baseOff;
  const __hip_bfloat16* pHi = xconv + (size_t)bHi * kXconvB + baseOff;

  f32x4 acc[4][4];
#pragma unroll
  for (int r = 0; r < 4; ++r)
#pragma unroll
    for (int c = 0; c < 4; ++c) acc[r][c] = (f32x4)0.f;

  const __hip_bfloat16* w1e = w1t + (size_t)e * kF * kH;
  const __hip_bfloat16* gB[4];
  short* lB[4];
#pragma unroll
  for (int it = 0; it < 4; ++it) {
    int s = it * 256 + tid;
    int m = (s >> 2) & 127, kk = s >> 9;
    int qq = (s & 3) ^ ((s >> 3) & 3);
    gB[it] = w1e + (size_t)(nbase + m) * kH + kk * 32 + qq * 8;
    lB[it] = &ldsB[s * 8];
  }

  for (int k0 = 0; k0 < kH; k0 += 64) {
    int koff = (k0 >> 6) * 2048;   // kblk * 2048 elts
    gld_lds16(pLo + koff,        &ldsA[(0 * 256 + tid) * 8]);
    gld_lds16(pHi + koff,        &ldsA[(1 * 256 + tid) * 8]);
    gld_lds16(pLo + koff + 1024, &ldsA[(2 * 256 + tid) * 8]);
    gld_lds16(pHi + koff + 1024, &ldsA[(3 * 256 + tid) * 8]);
#pragma unroll
    for (int it = 0; it < 4; ++it) gld_lds16(gB[it] + k0, lB[it]);
    __syncthreads();
#pragma unroll
    for (int kk = 0; kk < 2; ++kk) {
      short8 af[4], bfr[4];
#pragma unroll
      for (int r = 0; r < 4; ++r) {
        int mr = wm * 64 + r * 16 + lane16;
        af[r] = *(const short8*)&ldsA[(kk * 512 + mr * 4) * 8 + qx];
      }
#pragma unroll
      for (int c = 0; c < 4; ++c) {
        int mb = wn * 64 + c * 16 + lane16;
        bfr[c] = *(const short8*)&ldsB[(kk * 512 + mb * 4) * 8 + qx];
      }
#pragma unroll
      for (int r = 0; r < 4; ++r)
#pragma unroll
        for (int c = 0; c < 4; ++c)
          acc[r][c] = __builtin_amdgcn_mfma_f32_16x16x32_bf16(af[r], bfr[c], acc[r][c], 0, 0, 0);
    }
    __syncthreads();
  }

  // epilogue: gelu(acc+bias) -> LDS in hbuf-staged order -> contiguous 16B global stores
  __hip_bfloat16* htile = hbuf + (size_t)local * kHbufTile;
  unsigned short* uls = (unsigned short*)ldsbuf;
  int q4 = qf * 4;
#pragma unroll
  for (int c = 0; c < 4; ++c) {
    int nn = wn * 64 + c * 16 + lane16;           // n - nbase in [0,128)
    float bias = bf2f(b1[e * kF + nbase + nn]);
    int lbase = (nn >> 6) * 8192 + ((nn >> 5) & 1) * 4096 + (nn & 7);
    int qn = (nn >> 3) & 3;
#pragma unroll
    for (int r = 0; r < 4; ++r) {
#pragma unroll
      for (int g = 0; g < 4; ++g) {
        int m = wm * 64 + r * 16 + q4 + g;
        float v = acc[r][c][g] + bias;
        uls[lbase + (m * 4 + (qn ^ ((m >> 1) & 3))) * 8] = f2bfb(gelu_f(v));
      }
    }
  }
  __syncthreads();
  unsigned short* dstg = (unsigned short*)htile + (size_t)(nbase >> 6) * 8192;
#pragma unroll
  for (int i = 0; i < 8; ++i) {
    int s = i * 2048 + tid * 8;
    *(short8*)(dstg + s) = *(const short8*)(uls + s);
  }
}

// ---------------- GEMM2: out = (h @ W2[e] + b2) * score, f32 scatter ----------------
__global__ __launch_bounds__(256, 2)
void k_ffn2(const __hip_bfloat16* __restrict__ hbuf,
            const __hip_bfloat16* __restrict__ w2t,  // [E][H][F] bf16
            const __hip_bfloat16* __restrict__ b2,
            const float* __restrict__ wsel,
            const int* __restrict__ tileExpert,
            const int* __restrict__ tileBatch,
            const int* __restrict__ numTiles,
            int tileOff, int chunk,
            float* __restrict__ out) {
  int j = blockIdx.y;
  int local = blockIdx.x + 8 * (j / 6);
  if (local >= chunk) return;
  int tile = local + tileOff;
  if (tile >= *numTiles) return;
  int nbase = (j % 6) * 128;
  int e = tileExpert[tile];
  int tbraw[4];
  float sc[4];
#pragma unroll
  for (int s = 0; s < 4; ++s) {
    int bb = tileBatch[tile * 4 + s];
    tbraw[s] = bb;
    sc[s] = (bb >= 0) ? wsel[bb] : 0.f;
  }
  __shared__ __align__(16) short ldsA[8192];
  __shared__ __align__(16) short ldsB[8192];
  int tid = threadIdx.x;
  int lane = tid & 63, wid = tid >> 6;
  int wm = wid >> 1, wn = wid & 1;
  int lane16 = lane & 15, qf = lane >> 4;
  int swzl = (lane16 >> 1) & 3;
  int qx = (qf ^ swzl) * 8;

  f32x4 acc[4][4];
#pragma unroll
  for (int r = 0; r < 4; ++r)
#pragma unroll
    for (int c = 0; c < 4; ++c) acc[r][c] = (f32x4)0.f;

  const __hip_bfloat16* w2e = w2t + (size_t)e * kF * kH;
  const __hip_bfloat16* htile = hbuf + (size_t)local * kHbufTile;
  const __hip_bfloat16* gB[4];
  short* lA[4];
  short* lB[4];
  int aoff[4];
#pragma unroll
  for (int it = 0; it < 4; ++it) {
    int s = it * 256 + tid;
    int m = (s >> 2) & 127, kk = s >> 9;
    int qq = (s & 3) ^ ((s >> 3) & 3);
    aoff[it] = s * 8;
    gB[it] = w2e + (size_t)(nbase + m) * kF + kk * 32 + qq * 8;
    lA[it] = &ldsA[s * 8];
    lB[it] = &ldsB[s * 8];
  }

  for (int k0 = 0; k0 < kF; k0 += 64) {
#pragma unroll
    for (int it = 0; it < 4; ++it) gld_lds16(htile + k0 * 128 + aoff[it], lA[it]);
#pragma unroll
    for (int it = 0; it < 4; ++it) gld_lds16(gB[it] + k0, lB[it]);
    __syncthreads();
#pragma unroll
    for (int kk = 0; kk < 2; ++kk) {
      short8 af[4], bfr[4];
#pragma unroll
      for (int r = 0; r < 4; ++r) {
        int mr = wm * 64 + r * 16 + lane16;
        af[r] = *(const short8*)&ldsA[(kk * 512 + mr * 4) * 8 + qx];
      }
#pragma unroll
      for (int c = 0; c < 4; ++c) {
        int mb = wn * 64 + c * 16 + lane16;
        bfr[c] = *(const short8*)&ldsB[(kk * 512 + mb * 4) * 8 + qx];
      }
#pragma unroll
      for (int r = 0; r < 4; ++r)
#pragma unroll
        for (int c = 0; c < 4; ++c)
          acc[r][c] = __builtin_amdgcn_mfma_f32_16x16x32_bf16(af[r], bfr[c], acc[r][c], 0, 0, 0);
    }
    __syncthreads();
  }

  int q4 = qf * 4;
#pragma unroll
  for (int c = 0; c < 4; ++c) {
    int ncol = wn * 64 + c * 16 + lane16;
    float bias = bf2f(b2[e * kH + nbase + ncol]);
#pragma unroll
    for (int r = 0; r < 4; ++r) {
      int s = (wm * 64 + r * 16) >> 5;
      int bb = tbraw[s];
      if (bb < 0) continue;
      float scale = sc[s];
#pragma unroll
      for (int g = 0; g < 4; ++g) {
        int m = wm * 64 + r * 16 + q4 + g;
        float v = (acc[r][c][g] + bias) * scale;
        out[((size_t)(bb * kT + (m & 31))) * kH + nbase + ncol] = v;
      }
    }
  }
}

}  // namespace

extern "C" void kernel_launch(void* const* d_in, const int* in_sizes, int n_in,
                              void* d_out, int out_size, void* d_ws, size_t ws_size,
                              hipStream_t stream) {
  (void)in_sizes; (void)n_in; (void)out_size;
  float* out = (float*)d_out;

  char* ws = (char*)d_ws;
  size_t off = 0;
  auto alloc = [&](size_t bytes) -> char* {
    char* p = ws + off;
    off = (off + bytes + 255) & ~(size_t)255;
    return p;
  };
  int*   cntTk      = (int*)alloc(16);      // cnt[3] + ticket
  float* wsel       = (float*)alloc(kB * 4);
  int*   lists      = (int*)alloc((size_t)kE * kB * 4);
  int*   tileExpert = (int*)alloc(kMaxTiles * 4);
  int*   tileBatch  = (int*)alloc(kMaxTiles * 4 * 4);
  int*   numTiles   = (int*)alloc(4);
  __hip_bfloat16* w1t   = (__hip_bfloat16*)alloc((size_t)kE * kH * kF * 2);      // 14.2 MB
  __hip_bfloat16* w2t   = (__hip_bfloat16*)alloc((size_t)kE * kH * kF * 2);      // 14.2 MB
  __hip_bfloat16* xconv = (__hip_bfloat16*)alloc((size_t)kB * kXconvB * 2);      // 25.2 MB

  // adaptive hbuf chunk (deterministic in ws_size)
  size_t tileBytes = (size_t)kHbufTile * 2;  // 786432
  size_t avail = (ws_size > off + tileBytes) ? (ws_size - off) : tileBytes;
  int chunk = (int)(avail / tileBytes);
  if (chunk > kMaxChunk) chunk = kMaxChunk;
  if (chunk < 1) chunk = 1;
  __hip_bfloat16* hbuf = (__hip_bfloat16*)alloc((size_t)chunk * tileBytes);

  hipMemsetAsync(cntTk, 0, 16, stream);
  k_prep_x<<<kB, 256, 0, stream>>>(d_in[0], d_in[1], wsel, cntTk, lists,
                                   tileExpert, tileBatch, numTiles, xconv);
  k_transpose6<<<dim3(576, 1, 6), 256, 0, stream>>>(d_in[2], d_in[4], w1t, w2t);
  for (int toff = 0; toff < kMaxTiles; toff += chunk) {
    k_ffn1<<<dim3(8, 3 * chunk), 256, 0, stream>>>(xconv, w1t,
                                                   (const __hip_bfloat16*)d_in[3],
                                                   tileExpert, tileBatch,
                                                   numTiles, toff, hbuf);
    int rows2 = (chunk + 7) / 8;
    k_ffn2<<<dim3(8, 6 * rows2), 256, 0, stream>>>(hbuf, w2t,
                                                   (const __hip_bfloat16*)d_in[5], wsel,
                                                   tileExpert, tileBatch, numTiles,
                                                   toff, chunk, out);
  }
}